// Round 6
// baseline (156.611 us; speedup 1.0000x reference)
//
#include <hip/hip_runtime.h>
#include <cstdint>
#include <cstddef>
#include <math.h>

#define SEQ    2048
#define NBATCH 4
#define DIN    1024
#define DH     64

typedef __attribute__((ext_vector_type(8))) short  short8;   // 8 x bf16 (4 VGPRs)
typedef __attribute__((ext_vector_type(4))) float  floatx4;  // MFMA C/D

#define MFMA16(a, b, c) __builtin_amdgcn_mfma_f32_16x16x32_bf16((a), (b), (c), 0, 0, 0)

__device__ __forceinline__ unsigned short f2bf(float x) {
  unsigned u = __float_as_uint(x);
  return (unsigned short)((u + 0x8000u) >> 16);   // round-half-up; values finite
}
__device__ __forceinline__ float bf2f(unsigned short h) {
  return __uint_as_float(((unsigned)h) << 16);
}

// async global->LDS DMA, width 16: deposits at lds_base + lane*16.
__device__ __forceinline__ void async_cp16(const void* g, void* l) {
  __builtin_amdgcn_global_load_lds(
      (const __attribute__((address_space(1))) void*)g,
      (__attribute__((address_space(3))) void*)l, 16, 0, 0);
}

// volatile-asm W-fragment load: ordered among volatile asms, cannot be sunk.
template <int OFF>
__device__ __forceinline__ void gldw(short8 &d, unsigned long long a) {
  asm volatile("global_load_dwordx4 %0, %1, off offset:%2"
               : "=v"(d) : "v"(a), "n"(OFF));
}
#define WAITV(N) asm volatile("s_waitcnt vmcnt(" #N ")" ::: "memory")
#define SB()     __builtin_amdgcn_sched_barrier(0)
#define BAR()    __builtin_amdgcn_s_barrier()

// inline-asm LDS read: invisible to the compiler's DMA-alias tracking.
#define DSR(dst, ra, OFF)                                                      \
  asm volatile("ds_read_b128 %0, %1 offset:%2" : "=v"(dst) : "v"(ra), "n"(OFF))

// ======================= host-side numpy RNG replication =======================
namespace nprng {

struct PCG64 {
  __uint128_t state, inc;
  bool has_uint32;
  uint32_t uinteger;
};

static inline void pcg_step(PCG64 &g) {
  const __uint128_t MULT =
      (((__uint128_t)0x2360ed051fc65da4ULL) << 64) | 0x4385df649fccf645ULL;
  g.state = g.state * MULT + g.inc;
}

static inline uint64_t pcg_output(const PCG64 &g) {
  uint64_t hi = (uint64_t)(g.state >> 64);
  uint64_t lo = (uint64_t)g.state;
  uint64_t x = hi ^ lo;
  unsigned rot = (unsigned)(g.state >> 122) & 63u;
  return (x >> rot) | (x << ((64u - rot) & 63u));
}

static inline uint64_t pcg_next64(PCG64 &g) { pcg_step(g); return pcg_output(g); }

static inline uint32_t pcg_next32(PCG64 &g) {
  if (g.has_uint32) { g.has_uint32 = false; return g.uinteger; }
  uint64_t n = pcg_next64(g);
  g.has_uint32 = true;
  g.uinteger = (uint32_t)(n >> 32);
  return (uint32_t)(n & 0xffffffffu);
}

static inline void pcg_seed_from_seedseq0(PCG64 &g) {
  const uint32_t MULT_A = 0x931e8875u;
  const uint32_t MULT_B = 0x58f38dedu;
  const uint32_t MIX_L  = 0xca01f9ddu;
  const uint32_t MIX_R  = 0x4973f715u;
  uint32_t hc = 0x43b0d7e5u;  // INIT_A
  uint32_t pool[4];
  for (int i = 0; i < 4; i++) {
    uint32_t v = 0u;
    v ^= hc; hc *= MULT_A; v *= hc; v ^= v >> 16;
    pool[i] = v;
  }
  for (int is = 0; is < 4; is++) {
    for (int id = 0; id < 4; id++) {
      if (is == id) continue;
      uint32_t h = pool[is];
      h ^= hc; hc *= MULT_A; h *= hc; h ^= h >> 16;
      uint32_t r = (pool[id] * MIX_L) ^ (h * MIX_R);
      r ^= r >> 16;
      pool[id] = r;
    }
  }
  uint32_t hb = 0x8b51f9ddu;  // INIT_B
  uint32_t w[8];
  for (int i = 0; i < 8; i++) {
    uint32_t v = pool[i & 3];
    v ^= hb; hb *= MULT_B; v *= hb; v ^= v >> 16;
    w[i] = v;
  }
  uint64_t sv[4];
  for (int k = 0; k < 4; k++)
    sv[k] = (uint64_t)w[2 * k] | ((uint64_t)w[2 * k + 1] << 32);
  __uint128_t initstate = (((__uint128_t)sv[0]) << 64) | sv[1];
  __uint128_t initseq   = (((__uint128_t)sv[2]) << 64) | sv[3];
  g.state = 0; g.inc = (initseq << 1) | 1;
  pcg_step(g);
  g.state += initstate;
  pcg_step(g);
  g.has_uint32 = false; g.uinteger = 0;
}

static inline uint32_t bounded32(PCG64 &g, uint32_t rng /*inclusive max*/) {
  if (rng == 0) return 0;
  const uint32_t rng_excl = rng + 1u;
  uint64_t m = (uint64_t)pcg_next32(g) * (uint64_t)rng_excl;
  uint32_t leftover = (uint32_t)m;
  if (leftover < rng_excl) {
    const uint32_t threshold = (uint32_t)(0xffffffffu - rng) % rng_excl;
    while (leftover < threshold) {
      m = (uint64_t)pcg_next32(g) * (uint64_t)rng_excl;
      leftover = (uint32_t)m;
    }
  }
  return (uint32_t)(m >> 32);
}

static inline void choice3_2048(PCG64 &g, long long idx[3]) {
  const int pop = 2048, sz = 3;
  uint64_t hs[4] = { (uint64_t)-1, (uint64_t)-1, (uint64_t)-1, (uint64_t)-1 };
  const uint64_t mask = 3;
  for (int j = pop - sz; j < pop; j++) {
    uint64_t val = (uint64_t)bounded32(g, (uint32_t)j);
    uint64_t loc = val & mask;
    while (hs[loc] != (uint64_t)-1 && hs[loc] != val) loc = (loc + 1) & mask;
    if (hs[loc] == (uint64_t)-1) {
      hs[loc] = val;
      idx[j - pop + sz] = (long long)val;
    } else {
      loc = (uint64_t)j & mask;
      while (hs[loc] != (uint64_t)-1) loc = (loc + 1) & mask;
      hs[loc] = (uint64_t)j;
      idx[j - pop + sz] = (long long)j;
    }
  }
  for (int i = 2; i >= 1; i--) {
    uint32_t j = bounded32(g, (uint32_t)i);
    long long t = idx[j]; idx[j] = idx[i]; idx[i] = t;
  }
}

}  // namespace nprng

// ==================== kernel 0: W -> fragment-major bf16 WTc ==================
// WTc layout (short8 units): u = ((((p*8+kc)*2 + nch)*4 + ks)*2 + f)*64 + l
// unit content, element j: W[(kc*128 + ks*32 + (l>>4)*8 + j)*64 + nch*32 + f*16 + (l&15)]
__global__ __launch_bounds__(256) void wtrans_kernel(
    const float* __restrict__ Wq, const float* __restrict__ Wk,
    const float* __restrict__ Wv, unsigned short* __restrict__ WTc) {
  const int u = blockIdx.x * 256 + threadIdx.x;   // 0 .. 24575 short8 units
  const int l   = u & 63;
  const int fi  = (u >> 6) & 7;    // fi = ks*2 + f
  const int nch = (u >> 9) & 1;
  const int kc  = (u >> 10) & 7;
  const int p   = u >> 13;         // 0..2
  const int f   = fi & 1;
  const int ks  = fi >> 1;
  const float* W = (p == 0) ? Wq : (p == 1) ? Wk : Wv;
  const int n  = nch * 32 + f * 16 + (l & 15);
  const int k0 = kc * 128 + ks * 32 + ((l >> 4) * 8);
  short8 v;
#pragma unroll
  for (int j = 0; j < 8; j++) v[j] = (short)f2bf(W[(size_t)(k0 + j) * 64 + n]);
  *((short8*)WTc + u) = v;
}

// ============ projections: persistent blocks, CONTIGUOUS full-row staging =====
// Round 0-5 post-mortem: six schedules all pinned at ~40us, all pipes idle.
// Invariant was the ACCESS PATTERN: K-chunk reads = 512B slices at exact 4-KB
// row stride (channel aliasing) + per-chunk lockstep WTc reads. This kernel:
// grid 256 (1 block/CU, persistent), each block does 6 tiles of 16 rows x
// FULL K=1024 -> every stage is a CONTIGUOUS 64-KB read (16 width-16 DMAs per
// wave), double-buffered LDS (2x64KB), counted vmcnt(16) (drain only at end).
// W: the wave's 16-col slice for one proj = 32 frags = 128 VGPRs, reloaded 3x
// per block (once per proj phase) -- off the per-chunk critical path.
// ds_read bank conflicts: T2 both-sides XOR swizzle (unit^=row&7): linear DMA
// dest + pre-swizzled per-lane GLOBAL source + same XOR folded into read addr.
__global__ __launch_bounds__(256, 1) void proj_kernel(
    const float* __restrict__ xq, const float* __restrict__ xk,
    const float* __restrict__ xv, const unsigned short* __restrict__ WTc,
    const float* __restrict__ bq, const float* __restrict__ bk,
    const float* __restrict__ bv,
    unsigned short* __restrict__ Qf, unsigned short* __restrict__ Kf,
    unsigned short* __restrict__ Vf) {
  const int bid  = blockIdx.x;             // 0..255
  const int tid  = threadIdx.x;
  const int w    = tid >> 6;               // wave 0..3 -> cols w*16..w*16+15
  const int l    = tid & 63;
  const int quad = l >> 4;
  const int lx   = l & 15;

  __shared__ __align__(16) char XB[2][65536];   // 2 x (16 rows x 4096 B)
  __shared__ float Cs[16][68];

  const unsigned ldsb =
      (unsigned)(size_t)(__attribute__((address_space(3))) char*)&XB[0][0];
  // swizzled read addrs: row=lx, pos = unit ^ (row&7) folded into low bits
  const unsigned ra0 = ldsb + lx * 4096 + (((quad * 2 + 0) ^ (lx & 7)) << 4);
  const unsigned ra1 = ldsb + lx * 4096 + (((quad * 2 + 1) ^ (lx & 7)) << 4);
  const unsigned rb0 = ra0 + 65536;
  const unsigned rb1 = ra1 + 65536;

  // per-lane swizzled source byte offsets for the wave's 4 rows (j=0..3)
  unsigned so0, so1, so2, so3;
  {
#define SOX(j) (unsigned)((((l & ~7) + ((l & 7) ^ ((w * 4 + (j)) & 7)))) << 4)
    so0 = SOX(0); so1 = SOX(1); so2 = SOX(2); so3 = SOX(3);
#undef SOX
  }

  short8  Wreg[32];                        // 8 chunks x 4 ks, 128 VGPRs
  floatx4 acc;

#define LOADW(P)                                                               \
  { const unsigned long long wb = (unsigned long long)(const void*)WTc +       \
        (((size_t)(P) * 128 + (size_t)(w >> 1) * 8 + (w & 1)) * 1024) +        \
        (size_t)l * 16;                                                        \
    _Pragma("unroll")                                                          \
    for (int kc = 0; kc < 8; kc++) {                                           \
      const unsigned long long p0 = wb + kc * 16384ull;                        \
      const unsigned long long p1 = p0 + 4096ull;                              \
      gldw<0>(Wreg[kc * 4 + 0], p0); gldw<2048>(Wreg[kc * 4 + 1], p0);         \
      gldw<0>(Wreg[kc * 4 + 2], p1); gldw<2048>(Wreg[kc * 4 + 3], p1);         \
    } }

  // stage a 16-row x 4-KB tile (rows m0..m0+15 of X) into buffer B: each wave
  // 16 contiguous-1KB DMAs covering its 4 rows; source pre-swizzled per lane.
#define STAGE(XP, M0, B)                                                       \
  { const char* tb = (const char*)((XP) + (size_t)(M0) * DIN);                 \
    async_cp16(tb + (w*4+0)*4096 +    0 + so0, &XB[B][(w*16+ 0)*1024]);        \
    async_cp16(tb + (w*4+0)*4096 + 1024 + so0, &XB[B][(w*16+ 1)*1024]);        \
    async_cp16(tb + (w*4+0)*4096 + 2048 + so0, &XB[B][(w*16+ 2)*1024]);        \
    async_cp16(tb + (w*4+0)*4096 + 3072 + so0, &XB[B][(w*16+ 3)*1024]);        \
    async_cp16(tb + (w*4+1)*4096 +    0 + so1, &XB[B][(w*16+ 4)*1024]);        \
    async_cp16(tb + (w*4+1)*4096 + 1024 + so1, &XB[B][(w*16+ 5)*1024]);        \
    async_cp16(tb + (w*4+1)*4096 + 2048 + so1, &XB[B][(w*16+ 6)*1024]);        \
    async_cp16(tb + (w*4+1)*4096 + 3072 + so1, &XB[B][(w*16+ 7)*1024]);        \
    async_cp16(tb + (w*4+2)*4096 +    0 + so2, &XB[B][(w*16+ 8)*1024]);        \
    async_cp16(tb + (w*4+2)*4096 + 1024 + so2, &XB[B][(w*16+ 9)*1024]);        \
    async_cp16(tb + (w*4+2)*4096 + 2048 + so2, &XB[B][(w*16+10)*1024]);        \
    async_cp16(tb + (w*4+2)*4096 + 3072 + so2, &XB[B][(w*16+11)*1024]);        \
    async_cp16(tb + (w*4+3)*4096 +    0 + so3, &XB[B][(w*16+12)*1024]);        \
    async_cp16(tb + (w*4+3)*4096 + 1024 + so3, &XB[B][(w*16+13)*1024]);        \
    async_cp16(tb + (w*4+3)*4096 + 2048 + so3, &XB[B][(w*16+14)*1024]);        \
    async_cp16(tb + (w*4+3)*4096 + 3072 + so3, &XB[B][(w*16+15)*1024]); }

#define CVTM(f0, f1, wf)                                                       \
  { short8 a_;                                                                 \
    a_[0] = f2bf(f0[0]); a_[1] = f2bf(f0[1]); a_[2] = f2bf(f0[2]); a_[3] = f2bf(f0[3]); \
    a_[4] = f2bf(f1[0]); a_[5] = f2bf(f1[1]); a_[6] = f2bf(f1[2]); a_[7] = f2bf(f1[3]); \
    acc = MFMA16(a_, wf, acc); }

#define CONSUME(RA0v, RA1v)                                                    \
  acc = (floatx4){0.f, 0.f, 0.f, 0.f};                                         \
  _Pragma("unroll")                                                            \
  for (int kc = 0; kc < 8; kc++) {                                             \
    floatx4 x0, x1, x2, x3, x4, x5, x6, x7;                                    \
    DSR(x0, RA0v, kc * 512 + 0);   DSR(x1, RA1v, kc * 512 + 0);                \
    DSR(x2, RA0v, kc * 512 + 128); DSR(x3, RA1v, kc * 512 + 128);              \
    DSR(x4, RA0v, kc * 512 + 256); DSR(x5, RA1v, kc * 512 + 256);              \
    DSR(x6, RA0v, kc * 512 + 384); DSR(x7, RA1v, kc * 512 + 384);              \
    asm volatile("s_waitcnt lgkmcnt(0)" ::: "memory");                         \
    __builtin_amdgcn_sched_barrier(0);                                         \
    CVTM(x0, x1, Wreg[kc * 4 + 0]); CVTM(x2, x3, Wreg[kc * 4 + 1]);            \
    CVTM(x4, x5, Wreg[kc * 4 + 2]); CVTM(x6, x7, Wreg[kc * 4 + 3]);            \
  }

  // epilogue: 16x64 tile (+bias) via Cs, emit attn fragment layouts (r1-
  // verified mappings, 128 threads active).
#define EPI(P, M0v, BIASP)                                                     \
  { const float bb = (BIASP)[w * 16 + lx];                                     \
    _Pragma("unroll")                                                          \
    for (int i = 0; i < 4; i++) Cs[quad * 4 + i][w * 16 + lx] = acc[i] + bb;   \
    __syncthreads();                                                           \
    const int m0_ = (M0v);                                                     \
    const int b_  = m0_ >> 11;                                                 \
    const int s0  = m0_ & 2047;                                                \
    if (tid < 128) {                                                           \
      const int ll = tid & 63, lxx = ll & 15, qq = ll >> 4;                    \
      if ((P) == 0) {                                                          \
        const int s = tid >> 6;                                                \
        short8 v;                                                              \
        _Pragma("unroll")                                                      \
        for (int j = 0; j < 8; j++)                                            \
          v[j] = (short)f2bf(Cs[lxx][s * 32 + qq * 8 + j]);                    \
        char* dst = (char*)Qf + ((size_t)(b_ * 128 + (s0 >> 4))) * 2048 +      \
                    s * 1024 + ll * 16;                                        \
        *(short8*)dst = v;                                                     \
      } else if ((P) == 1) {                                                   \
        const int s = tid >> 6;                                                \
        const int c = (s0 >> 4) & 3;                                           \
        short8 v;                                                              \
        _Pragma("unroll")                                                      \
        for (int j = 0; j < 8; j++)                                            \
          v[j] = (short)f2bf(Cs[lxx][s * 32 + qq * 8 + j]);                    \
        char* dst = (char*)Kf + ((size_t)(b_ * 32 + (s0 >> 6))) * 8192 +       \
                    (c * 2 + s) * 1024 + ll * 16;                              \
        *(short8*)dst = v;                                                     \
      } else {                                                                 \
        const int h  = (s0 >> 4) & 1;                                          \
        const int sf = (s0 >> 5) & 1;                                          \
        const int c  = tid >> 5;                                               \
        const int lv = h * 32 + (tid & 31);                                    \
        const int q2 = (lv >> 4) & 1;                                          \
        const int lxv = lv & 15;                                               \
        short8 v;                                                              \
        _Pragma("unroll")                                                      \
        for (int j = 0; j < 8; j++)                                            \
          v[j] = (short)f2bf(Cs[q2 * 8 + j][c * 16 + lxv]);                    \
        char* dst = (char*)Vf + ((size_t)(b_ * 32 + (s0 >> 6))) * 8192 +       \
                    (sf * 4 + c) * 1024 + lv * 16;                             \
        *(short8*)dst = v;                                                     \
      }                                                                        \
    } }

  const int m0a = bid * 16;            // tiles k even
  const int m0b = bid * 16 + 4096;     // tiles k odd

  // prologue: W(proj0) + tile0
  LOADW(0);
  STAGE(xq, m0a, 0);
  // k=0 (proj0, buf0)
  STAGE(xq, m0b, 1);
  WAITV(16); SB(); BAR();
  CONSUME(ra0, ra1);
  EPI(0, m0a, bq);
  // k=1 (proj0, buf1)
  STAGE(xk, m0a, 0);
  WAITV(16); SB(); BAR();
  CONSUME(rb0, rb1);
  EPI(0, m0b, bq);
  // k=2 (proj1, buf0) — W reload
  LOADW(1);
  STAGE(xk, m0b, 1);
  WAITV(16); SB(); BAR();
  CONSUME(ra0, ra1);
  EPI(1, m0a, bk);
  // k=3 (proj1, buf1)
  STAGE(xv, m0a, 0);
  WAITV(16); SB(); BAR();
  CONSUME(rb0, rb1);
  EPI(1, m0b, bk);
  // k=4 (proj2, buf0) — W reload
  LOADW(2);
  STAGE(xv, m0b, 1);
  WAITV(16); SB(); BAR();
  CONSUME(ra0, ra1);
  EPI(2, m0a, bv);
  // k=5 (proj2, buf1) — tail drain
  WAITV(0); SB(); BAR();
  CONSUME(rb0, rb1);
  EPI(2, m0b, bv);

#undef LOADW
#undef STAGE
#undef CVTM
#undef CONSUME
#undef EPI
}

// ============ flash attention: fragment-major direct loads, 1 barrier =========
// grid (128, 4), 256 threads (4 waves). Block = 16 q-rows; wave w processes
// key-tiles t = w, w+4, ... with independent online-softmax state; merged once.
__global__ __launch_bounds__(256, 2) void attn_kernel(
    const unsigned short* __restrict__ Qf, const unsigned short* __restrict__ Kf,
    const unsigned short* __restrict__ Vf, float* __restrict__ out,
    int R0, int C0, int R1, int C1, int R2, int C2) {
  const int b    = blockIdx.y;
  const int bx   = blockIdx.x;
  const int qi   = (bx & 1) ? (127 - (bx >> 1)) : (bx >> 1);  // heavy/light pairing
  const int q0   = qi * 16;
  const int tid  = threadIdx.x;
  const int w    = tid >> 6;
  const int l    = tid & 63;
  const int quad = l >> 4;
  const int lx   = l & 15;

  __shared__ unsigned short Ps[4][16][72];
  __shared__ float Os[4][16][64];
  __shared__ float mS[4][16], lS[4][16];
  __shared__ float lgS[3];
  __shared__ int   lgF[3];

  const char* Qc = (const char*)Qf + ((size_t)(b * 128 + qi)) * 2048 + l * 16;
  const short8 aq0 = *(const short8*)Qc;
  const short8 aq1 = *(const short8*)(Qc + 1024);

  floatx4 O[4];
  float m_i[4], l_i[4];
#pragma unroll
  for (int c = 0; c < 4; c++) O[c] = (floatx4){0.f, 0.f, 0.f, 0.f};
#pragma unroll
  for (int i = 0; i < 4; i++) { m_i[i] = -INFINITY; l_i[i] = 0.f; }

  const int T = (q0 + 79) >> 6;   // key-tiles needed (64 keys each)

  for (int t = w; t < T; t += 4) {
    const int k0 = t << 6;
    const bool mT = (t == T - 1);

    const char* Kc = (const char*)Kf + ((size_t)(b * 32 + t)) * 8192 + l * 16;
    const char* Vc = (const char*)Vf + ((size_t)(b * 32 + t)) * 8192 + l * 16;
    short8 kf[8], vf[8];
#pragma unroll
    for (int f = 0; f < 8; f++) {
      kf[f] = *(const short8*)(Kc + f * 1024);
      vf[f] = *(const short8*)(Vc + f * 1024);
    }

    floatx4 sc[4];
    __builtin_amdgcn_s_setprio(1);
#pragma unroll
    for (int c = 0; c < 4; c++) {
      sc[c] = (floatx4){0.f, 0.f, 0.f, 0.f};
      sc[c] = MFMA16(aq0, kf[2 * c], sc[c]);
      sc[c] = MFMA16(aq1, kf[2 * c + 1], sc[c]);
    }
    __builtin_amdgcn_s_setprio(0);

    float mt[4], al[4];
#pragma unroll
    for (int i = 0; i < 4; i++) {
      const int rowg = q0 + quad * 4 + i;
      float vmax = -INFINITY;
#pragma unroll
      for (int c = 0; c < 4; c++) {
        float v = sc[c][i] * 0.125f;
        if (mT && (k0 + 16 * c + lx) > rowg) v = -INFINITY;
        sc[c][i] = v;
        vmax = fmaxf(vmax, v);
      }
      mt[i] = vmax;
    }
#pragma unroll
    for (int i = 0; i < 4; i++) {
#pragma unroll
      for (int off = 8; off >= 1; off >>= 1)
        mt[i] = fmaxf(mt[i], __shfl_xor(mt[i], off));
      const float mn = fmaxf(m_i[i], mt[i]);
      al[i] = __expf(m_i[i] - mn);
      m_i[i] = mn;
      float s = 0.f;
#pragma unroll
      for (int c = 0; c < 4; c++) {
        float p = __expf(sc[c][i] - mn);
        Ps[w][quad * 4 + i][16 * c + lx] = f2bf(p);
        s += p;
      }
#pragma unroll
      for (int off = 8; off >= 1; off >>= 1) s += __shfl_xor(s, off);
      l_i[i] = l_i[i] * al[i] + s;
    }
#pragma unroll
    for (int c = 0; c < 4; c++)
#pragma unroll
      for (int i = 0; i < 4; i++) O[c][i] *= al[i];
    asm volatile("" ::: "memory");  // keep ds_reads below the ds_writes above
    const short8 pf0 = *(const short8*)&Ps[w][lx][quad * 8];
    const short8 pf1 = *(const short8*)&Ps[w][lx][32 + quad * 8];
    __builtin_amdgcn_s_setprio(1);
#pragma unroll
    for (int c = 0; c < 4; c++) {
      O[c] = MFMA16(pf0, vf[c],     O[c]);
      O[c] = MFMA16(pf1, vf[4 + c], O[c]);
    }
    __builtin_amdgcn_s_setprio(0);
  }

  // deposit per-wave state
  if (lx == 0) {
#pragma unroll
    for (int i = 0; i < 4; i++) {
      mS[w][quad * 4 + i] = m_i[i];
      lS[w][quad * 4 + i] = l_i[i];
    }
  }
#pragma unroll
  for (int c = 0; c < 4; c++)
#pragma unroll
    for (int i = 0; i < 4; i++) Os[w][quad * 4 + i][16 * c + lx] = O[c][i];

  // wave 0: logits for global pairs above the diagonal (lane l owns dim d=l)
  if (w == 0) {
#pragma unroll
    for (int p = 0; p < 3; p++) {
      const int R = (p == 0) ? R0 : (p == 1) ? R1 : R2;
      const int C = (p == 0) ? C0 : (p == 1) ? C1 : C2;
      const int act = (R >= q0 && R < q0 + 16 && C > R);
      float d = 0.f;
      if (act) {
        const int dd = l;
        const char* qa = (const char*)Qf + ((size_t)(b * 128 + (R >> 4))) * 2048 +
                         (dd >> 5) * 1024 + ((R & 15) + ((dd >> 3) & 3) * 16) * 16 + (dd & 7) * 2;
        const char* ka = (const char*)Kf + ((size_t)(b * 32 + (C >> 6))) * 8192 +
                         (((C >> 4) & 3) * 2 + (dd >> 5)) * 1024 +
                         ((C & 15) + ((dd >> 3) & 3) * 16) * 16 + (dd & 7) * 2;
        d = bf2f(*(const unsigned short*)qa) * bf2f(*(const unsigned short*)ka);
#pragma unroll
        for (int off = 32; off >= 1; off >>= 1) d += __shfl_xor(d, off);
        d *= 0.125f;
      }
      if (l == 0) { lgF[p] = act; lgS[p] = d; }
    }
  }
  __syncthreads();

  // merge the 4 wave states (+ pair fixups), normalize, store
  {
    const int row = tid >> 4;          // 0..15
    const int d0  = (tid & 15) * 4;    // 0..60
    const int Rs[3] = {R0, R1, R2};
    const int Cs3[3] = {C0, C1, C2};

    float mf = -INFINITY;
#pragma unroll
    for (int w4 = 0; w4 < 4; w4++) mf = fmaxf(mf, mS[w4][row]);
#pragma unroll
    for (int p = 0; p < 3; p++)
      if (lgF[p] && (Rs[p] - q0) == row) mf = fmaxf(mf, lgS[p]);

    float lf = 0.f;
    float o0 = 0.f, o1 = 0.f, o2 = 0.f, o3 = 0.f;
#pragma unroll
    for (int w4 = 0; w4 < 4; w4++) {
      const float a = __expf(mS[w4][row] - mf);
      lf += a * lS[w4][row];
      const float* op = &Os[w4][row][d0];
      o0 += a * op[0]; o1 += a * op[1]; o2 += a * op[2]; o3 += a * op[3];
    }
#pragma unroll
    for (int p = 0; p < 3; p++) {
      if (lgF[p] && (Rs[p] - q0) == row) {
        const float pe = __expf(lgS[p] - mf);
        lf += pe;
        const int C = Cs3[p];
        float vv[4];
#pragma unroll
        for (int j = 0; j < 4; j++) {
          const int dim = d0 + j;
          const char* va = (const char*)Vf + ((size_t)(b * 32 + (C >> 6))) * 8192 +
                           (((C >> 5) & 1) * 4 + (dim >> 4)) * 1024 +
                           ((dim & 15) + ((C >> 3) & 3) * 16) * 16 + (C & 7) * 2;
          vv[j] = bf2f(*(const unsigned short*)va);
        }
        o0 += pe * vv[0]; o1 += pe * vv[1]; o2 += pe * vv[2]; o3 += pe * vv[3];
      }
    }
    const float inv = 1.0f / lf;
    float4 r;
    r.x = o0 * inv; r.y = o1 * inv; r.z = o2 * inv; r.w = o3 * inv;
    *(float4*)(out + ((size_t)b * SEQ + q0 + row) * 64 + d0) = r;
  }
}

// ================================= launch =====================================
extern "C" void kernel_launch(void* const* d_in, const int* in_sizes, int n_in,
                              void* d_out, int out_size, void* d_ws,
                              size_t ws_size, hipStream_t stream) {
  const float* xq = (const float*)d_in[0];
  const float* xk = (const float*)d_in[1];
  const float* xv = (const float*)d_in[2];
  const float* Wq = (const float*)d_in[3];
  const float* bq = (const float*)d_in[4];
  const float* Wk = (const float*)d_in[5];
  const float* bk = (const float*)d_in[6];
  const float* Wv = (const float*)d_in[7];
  const float* bv = (const float*)d_in[8];
  float* out = (float*)d_out;

  // workspace (bf16): Qf 1MB, Kf 1MB, Vf 1MB, WTc 384KB (fragment-major layouts)
  unsigned short* Qf  = (unsigned short*)d_ws;
  unsigned short* Kf  = Qf + (size_t)NBATCH * SEQ * 64;
  unsigned short* Vf  = Kf + (size_t)NBATCH * SEQ * 64;
  unsigned short* WTc = Vf + (size_t)NBATCH * SEQ * 64;

  nprng::PCG64 g;
  nprng::pcg_seed_from_seedseq0(g);
  long long rows[3], cols[3];
  nprng::choice3_2048(g, rows);
  nprng::choice3_2048(g, cols);

  wtrans_kernel<<<96, 256, 0, stream>>>(Wq, Wk, Wv, WTc);

  proj_kernel<<<256, 256, 0, stream>>>(xq, xk, xv, WTc, bq, bk, bv, Qf, Kf, Vf);

  dim3 agrid(SEQ / 16, NBATCH);
  attn_kernel<<<agrid, 256, 0, stream>>>(
      Qf, Kf, Vf, out, (int)rows[0], (int)cols[0], (int)rows[1], (int)cols[1],
      (int)rows[2], (int)cols[2]);
}

// Round 7
// 150.897 us; speedup vs baseline: 1.0379x; 1.0379x over previous
//
#include <hip/hip_runtime.h>
#include <cstdint>
#include <cstddef>
#include <math.h>

#define SEQ    2048
#define NBATCH 4
#define DIN    1024
#define DH     64

typedef __attribute__((ext_vector_type(8))) short  short8;   // 8 x bf16 (4 VGPRs)
typedef __attribute__((ext_vector_type(4))) float  floatx4;  // MFMA C/D
typedef __attribute__((ext_vector_type(2))) unsigned uint2v; // ds_write_b64 payload

#define MFMA16(a, b, c) __builtin_amdgcn_mfma_f32_16x16x32_bf16((a), (b), (c), 0, 0, 0)

__device__ __forceinline__ unsigned short f2bf(float x) {
  unsigned u = __float_as_uint(x);
  return (unsigned short)((u + 0x8000u) >> 16);   // round-half-up; values finite
}
__device__ __forceinline__ float bf2f(unsigned short h) {
  return __uint_as_float(((unsigned)h) << 16);
}
__device__ __forceinline__ unsigned pk2(float a, float b) {
  return (unsigned)f2bf(a) | ((unsigned)f2bf(b) << 16);
}

// ---- volatile-asm memory ops: total order, exact vmcnt/lgkmcnt ledger -------
template <int OFF>
__device__ __forceinline__ void gldx(floatx4 &d, unsigned long long a) {
  asm volatile("global_load_dwordx4 %0, %1, off offset:%2"
               : "=v"(d) : "v"(a), "n"(OFF));
}
template <int OFF>
__device__ __forceinline__ void gldw(short8 &d, unsigned long long a) {
  asm volatile("global_load_dwordx4 %0, %1, off offset:%2"
               : "=v"(d) : "v"(a), "n"(OFF));
}
__device__ __forceinline__ void gldf(float &d, unsigned long long a) {
  asm volatile("global_load_dword %0, %1, off" : "=v"(d) : "v"(a));
}
#define WAITV(N) asm volatile("s_waitcnt vmcnt(" #N ")" ::: "memory")
#define WAITL()  asm volatile("s_waitcnt lgkmcnt(0)" ::: "memory")
#define SB()     __builtin_amdgcn_sched_barrier(0)
#define BAR()    __builtin_amdgcn_s_barrier()
#define DSR(dst, ra, OFF)                                                      \
  asm volatile("ds_read_b128 %0, %1 offset:%2" : "=v"(dst) : "v"(ra), "n"(OFF))
#define DSW(addr, val, OFF)                                                    \
  asm volatile("ds_write_b64 %0, %1 offset:%2" :: "v"(addr), "v"(val), "n"(OFF) : "memory")

// ======================= host-side numpy RNG replication =======================
namespace nprng {

struct PCG64 {
  __uint128_t state, inc;
  bool has_uint32;
  uint32_t uinteger;
};

static inline void pcg_step(PCG64 &g) {
  const __uint128_t MULT =
      (((__uint128_t)0x2360ed051fc65da4ULL) << 64) | 0x4385df649fccf645ULL;
  g.state = g.state * MULT + g.inc;
}

static inline uint64_t pcg_output(const PCG64 &g) {
  uint64_t hi = (uint64_t)(g.state >> 64);
  uint64_t lo = (uint64_t)g.state;
  uint64_t x = hi ^ lo;
  unsigned rot = (unsigned)(g.state >> 122) & 63u;
  return (x >> rot) | (x << ((64u - rot) & 63u));
}

static inline uint64_t pcg_next64(PCG64 &g) { pcg_step(g); return pcg_output(g); }

static inline uint32_t pcg_next32(PCG64 &g) {
  if (g.has_uint32) { g.has_uint32 = false; return g.uinteger; }
  uint64_t n = pcg_next64(g);
  g.has_uint32 = true;
  g.uinteger = (uint32_t)(n >> 32);
  return (uint32_t)(n & 0xffffffffu);
}

static inline void pcg_seed_from_seedseq0(PCG64 &g) {
  const uint32_t MULT_A = 0x931e8875u;
  const uint32_t MULT_B = 0x58f38dedu;
  const uint32_t MIX_L  = 0xca01f9ddu;
  const uint32_t MIX_R  = 0x4973f715u;
  uint32_t hc = 0x43b0d7e5u;  // INIT_A
  uint32_t pool[4];
  for (int i = 0; i < 4; i++) {
    uint32_t v = 0u;
    v ^= hc; hc *= MULT_A; v *= hc; v ^= v >> 16;
    pool[i] = v;
  }
  for (int is = 0; is < 4; is++) {
    for (int id = 0; id < 4; id++) {
      if (is == id) continue;
      uint32_t h = pool[is];
      h ^= hc; hc *= MULT_A; h *= hc; h ^= h >> 16;
      uint32_t r = (pool[id] * MIX_L) ^ (h * MIX_R);
      r ^= r >> 16;
      pool[id] = r;
    }
  }
  uint32_t hb = 0x8b51f9ddu;  // INIT_B
  uint32_t w[8];
  for (int i = 0; i < 8; i++) {
    uint32_t v = pool[i & 3];
    v ^= hb; hb *= MULT_B; v *= hb; v ^= v >> 16;
    w[i] = v;
  }
  uint64_t sv[4];
  for (int k = 0; k < 4; k++)
    sv[k] = (uint64_t)w[2 * k] | ((uint64_t)w[2 * k + 1] << 32);
  __uint128_t initstate = (((__uint128_t)sv[0]) << 64) | sv[1];
  __uint128_t initseq   = (((__uint128_t)sv[2]) << 64) | sv[3];
  g.state = 0; g.inc = (initseq << 1) | 1;
  pcg_step(g);
  g.state += initstate;
  pcg_step(g);
  g.has_uint32 = false; g.uinteger = 0;
}

static inline uint32_t bounded32(PCG64 &g, uint32_t rng /*inclusive max*/) {
  if (rng == 0) return 0;
  const uint32_t rng_excl = rng + 1u;
  uint64_t m = (uint64_t)pcg_next32(g) * (uint64_t)rng_excl;
  uint32_t leftover = (uint32_t)m;
  if (leftover < rng_excl) {
    const uint32_t threshold = (uint32_t)(0xffffffffu - rng) % rng_excl;
    while (leftover < threshold) {
      m = (uint64_t)pcg_next32(g) * (uint64_t)rng_excl;
      leftover = (uint32_t)m;
    }
  }
  return (uint32_t)(m >> 32);
}

static inline void choice3_2048(PCG64 &g, long long idx[3]) {
  const int pop = 2048, sz = 3;
  uint64_t hs[4] = { (uint64_t)-1, (uint64_t)-1, (uint64_t)-1, (uint64_t)-1 };
  const uint64_t mask = 3;
  for (int j = pop - sz; j < pop; j++) {
    uint64_t val = (uint64_t)bounded32(g, (uint32_t)j);
    uint64_t loc = val & mask;
    while (hs[loc] != (uint64_t)-1 && hs[loc] != val) loc = (loc + 1) & mask;
    if (hs[loc] == (uint64_t)-1) {
      hs[loc] = val;
      idx[j - pop + sz] = (long long)val;
    } else {
      loc = (uint64_t)j & mask;
      while (hs[loc] != (uint64_t)-1) loc = (loc + 1) & mask;
      hs[loc] = (uint64_t)j;
      idx[j - pop + sz] = (long long)j;
    }
  }
  for (int i = 2; i >= 1; i--) {
    uint32_t j = bounded32(g, (uint32_t)i);
    long long t = idx[j]; idx[j] = idx[i]; idx[i] = t;
  }
}

}  // namespace nprng

// ==================== kernel 0: W -> fragment-major bf16 WTc ==================
// WTc layout (short8 units): u = ((((p*8+kc)*2 + nch)*4 + ks)*2 + f)*64 + l
// unit content, element j: W[(kc*128 + ks*32 + (l>>4)*8 + j)*64 + nch*32 + f*16 + (l&15)]
__global__ __launch_bounds__(256) void wtrans_kernel(
    const float* __restrict__ Wq, const float* __restrict__ Wk,
    const float* __restrict__ Wv, unsigned short* __restrict__ WTc) {
  const int u = blockIdx.x * 256 + threadIdx.x;   // 0 .. 24575 short8 units
  const int l   = u & 63;
  const int fi  = (u >> 6) & 7;    // fi = ks*2 + f
  const int nch = (u >> 9) & 1;
  const int kc  = (u >> 10) & 7;
  const int p   = u >> 13;         // 0..2
  const int f   = fi & 1;
  const int ks  = fi >> 1;
  const float* W = (p == 0) ? Wq : (p == 1) ? Wk : Wv;
  const int n  = nch * 32 + f * 16 + (l & 15);
  const int k0 = kc * 128 + ks * 32 + ((l >> 4) * 8);
  short8 v;
#pragma unroll
  for (int j = 0; j < 8; j++) v[j] = (short)f2bf(W[(size_t)(k0 + j) * 64 + n]);
  *((short8*)WTc + u) = v;
}

// ======== projections: all-asm loop, stage-side bf16 cvt, exact vmcnt ledger ==
// grid 768 x 256 thr (4 waves). Block = 32 rows; wave w: row-half (w&1),
// col-half (w>>1). K=1024 in 8 chunks of 128.
// X path: 4 volatile dwordx4/wave/chunk (128-B segments, full line use) ->
// f2bf pack in VALU -> ds_write_b64 into a DOUBLE-buffered bf16 [32][256B]
// tile (2x8 KB). Write AND read both fold the XOR swizzle u^=(row&7) on 16-B
// units -> ds_read_b128 a-fragments are conflict-free; consume = 4 ds_read +
// 8 MFMA only (conversion moved off the barrier-serialized critical path).
// EVERY memory op in the loop is volatile asm (X, W, ds_write, ds_read) and
// bias is asm-loaded before the prologue, so the vmcnt ledger is exact:
// prologue 26 outstanding, steady vmcnt(12) per chunk (drains exactly chunk
// k's 4 X + 8 W), vmcnt(0) only at the final chunk. Barriers are raw
// s_barrier + lgkmcnt(0) -- vmcnt is NEVER drained mid-loop and the compiler
// owns zero loop memory ops, so it cannot add or shift a single wait.
__global__ __launch_bounds__(256, 3) void proj_kernel(
    const float* __restrict__ xq, const float* __restrict__ xk,
    const float* __restrict__ xv, const unsigned short* __restrict__ WTc,
    const float* __restrict__ bq, const float* __restrict__ bk,
    const float* __restrict__ bv,
    unsigned short* __restrict__ Qf, unsigned short* __restrict__ Kf,
    unsigned short* __restrict__ Vf) {
  const int m0g  = blockIdx.x * 32;        // 0..24544
  const int proj = m0g >> 13;              // 0,1,2
  const int m0   = m0g & 8191;             // row within proj
  const float* X    = (proj == 0) ? xq : (proj == 1) ? xk : xv;
  const float* bias = (proj == 0) ? bq : (proj == 1) ? bk : bv;

  const int tid  = threadIdx.x;
  const int w    = tid >> 6;
  const int l    = tid & 63;
  const int quad = l >> 4;
  const int lx   = l & 15;
  const int mr   = (w & 1) * 16;           // wave's row half
  const int nc   = (w >> 1) * 32;          // wave's col half

  __shared__ __align__(16) char LDSbuf[2 * 8192];   // 2 x [32 rows][256 B bf16]

  // ---- bias via asm FIRST: keeps the vmcnt ledger exact (2 oldest ops) ----
  float bb0, bb1;
  gldf(bb0, (unsigned long long)(const void*)(bias + nc + lx));
  gldf(bb1, (unsigned long long)(const void*)(bias + nc + 16 + lx));

  // ---- X stage addressing: lane covers row 8w+(l>>3), bytes (l&7)*16+j*128 --
  const int srow = 8 * w + (l >> 3);
  const unsigned long long xab = (unsigned long long)(const void*)
      ((const char*)(X + (size_t)(m0 + srow) * DIN) + (l & 7) * 16);

  // ---- LDS write addrs (swizzled): unit u=(j<<2)|u0, byte=(u^s7)*16+8*(l&1) -
  const unsigned ldsb =
      (unsigned)(size_t)(__attribute__((address_space(3))) char*)LDSbuf;
  const int s7 = srow & 7;
  const int u0 = (l >> 1) & 3;
  const unsigned wbase = ldsb + srow * 256 + (l & 1) * 8;
  const unsigned wr0 = wbase + (unsigned)(((0 << 2) | u0) ^ s7) * 16;
  const unsigned wr1 = wbase + (unsigned)(((1 << 2) | u0) ^ s7) * 16;
  const unsigned wr2 = wbase + (unsigned)(((2 << 2) | u0) ^ s7) * 16;
  const unsigned wr3 = wbase + (unsigned)(((3 << 2) | u0) ^ s7) * 16;

  // ---- LDS read addrs (same swizzle): row mr+lx, unit (ks<<2)|quad ^ (lx&7) -
  const unsigned rbase = ldsb + (mr + lx) * 256;
  const unsigned rd0 = rbase + (unsigned)(((0 << 2) | quad) ^ (lx & 7)) * 16;
  const unsigned rd1 = rbase + (unsigned)(((1 << 2) | quad) ^ (lx & 7)) * 16;
  const unsigned rd2 = rbase + (unsigned)(((2 << 2) | quad) ^ (lx & 7)) * 16;
  const unsigned rd3 = rbase + (unsigned)(((3 << 2) | quad) ^ (lx & 7)) * 16;

  // ---- W fragments (r5-verified mapping) ----
  const unsigned long long wab =
      (unsigned long long)(const void*)((const short8*)WTc +
                                        ((size_t)(proj * 16 + (w >> 1))) * 512 + l);

  floatx4 acc0 = {0.f, 0.f, 0.f, 0.f}, acc1 = acc0;
  short8  wa[8], wb[8];
  floatx4 ra0, ra1, ra2, ra3, rb0, rb1, rb2, rb3;

#define LX(KC, R0, R1, R2, R3)                                                 \
  gldx<(KC)*512 +   0>(R0, xab); gldx<(KC)*512 + 128>(R1, xab);                \
  gldx<(KC)*512 + 256>(R2, xab); gldx<(KC)*512 + 384>(R3, xab);

#define LW(KC, WBUF)                                                           \
  { const unsigned long long p0 = wab + (KC) * 16384ull;                       \
    const unsigned long long p1 = p0 + 4096ull;                                \
    gldw<   0>(WBUF[0], p0); gldw<1024>(WBUF[1], p0);                          \
    gldw<2048>(WBUF[2], p0); gldw<3072>(WBUF[3], p0);                          \
    gldw<   0>(WBUF[4], p1); gldw<1024>(WBUF[5], p1);                          \
    gldw<2048>(WBUF[6], p1); gldw<3072>(WBUF[7], p1); }

#define CW(R0, R1, R2, R3, BOFF)                                               \
  { uint2v p0_, p1_, p2_, p3_;                                                 \
    p0_[0] = pk2(R0[0], R0[1]); p0_[1] = pk2(R0[2], R0[3]);                    \
    p1_[0] = pk2(R1[0], R1[1]); p1_[1] = pk2(R1[2], R1[3]);                    \
    p2_[0] = pk2(R2[0], R2[1]); p2_[1] = pk2(R2[2], R2[3]);                    \
    p3_[0] = pk2(R3[0], R3[1]); p3_[1] = pk2(R3[2], R3[3]);                    \
    DSW(wr0, p0_, BOFF); DSW(wr1, p1_, BOFF);                                  \
    DSW(wr2, p2_, BOFF); DSW(wr3, p3_, BOFF); }

#define CONSUME(BOFF, WBUF)                                                    \
  { floatx4 a0_, a1_, a2_, a3_;                                                \
    DSR(a0_, rd0, BOFF); DSR(a1_, rd1, BOFF);                                  \
    DSR(a2_, rd2, BOFF); DSR(a3_, rd3, BOFF);                                  \
    WAITL(); SB();                                                             \
    acc0 = MFMA16(*(short8*)&a0_, WBUF[0], acc0);                              \
    acc1 = MFMA16(*(short8*)&a0_, WBUF[1], acc1);                              \
    acc0 = MFMA16(*(short8*)&a1_, WBUF[2], acc0);                              \
    acc1 = MFMA16(*(short8*)&a1_, WBUF[3], acc1);                              \
    acc0 = MFMA16(*(short8*)&a2_, WBUF[4], acc0);                              \
    acc1 = MFMA16(*(short8*)&a2_, WBUF[5], acc1);                              \
    acc0 = MFMA16(*(short8*)&a3_, WBUF[6], acc0);                              \
    acc1 = MFMA16(*(short8*)&a3_, WBUF[7], acc1); }

  // prologue: bias(2) + chunk0 (4X+8W) + chunk1 (4X+8W) = 26 outstanding
  LX(0, ra0, ra1, ra2, ra3); LW(0, wa);
  LX(1, rb0, rb1, rb2, rb3); LW(1, wb);

  // k=0
  WAITV(12); SB();
  CW(ra0, ra1, ra2, ra3, 0);    LX(2, ra0, ra1, ra2, ra3);
  WAITL(); BAR(); CONSUME(0, wa);    LW(2, wa); BAR();
  // k=1
  WAITV(12); SB();
  CW(rb0, rb1, rb2, rb3, 8192); LX(3, rb0, rb1, rb2, rb3);
  WAITL(); BAR(); CONSUME(8192, wb); LW(3, wb); BAR();
  // k=2
  WAITV(12); SB();
  CW(ra0, ra1, ra2, ra3, 0);    LX(4, ra0, ra1, ra2, ra3);
  WAITL(); BAR(); CONSUME(0, wa);    LW(4, wa); BAR();
  // k=3
  WAITV(12); SB();
  CW(rb0, rb1, rb2, rb3, 8192); LX(5, rb0, rb1, rb2, rb3);
  WAITL(); BAR(); CONSUME(8192, wb); LW(5, wb); BAR();
  // k=4
  WAITV(12); SB();
  CW(ra0, ra1, ra2, ra3, 0);    LX(6, ra0, ra1, ra2, ra3);
  WAITL(); BAR(); CONSUME(0, wa);    LW(6, wa); BAR();
  // k=5
  WAITV(12); SB();
  CW(rb0, rb1, rb2, rb3, 8192); LX(7, rb0, rb1, rb2, rb3);
  WAITL(); BAR(); CONSUME(8192, wb); LW(7, wb); BAR();
  // k=6 (no further issues; outstanding = LX7+LW7 = 12)
  WAITV(12); SB();
  CW(ra0, ra1, ra2, ra3, 0);
  WAITL(); BAR(); CONSUME(0, wa); BAR();
  // k=7 (tail drain)
  WAITV(0); SB();
  CW(rb0, rb1, rb2, rb3, 8192);
  WAITL(); BAR(); CONSUME(8192, wb);

#undef LX
#undef LW
#undef CW
#undef CONSUME

  __syncthreads();   // all k=7 LDS reads done before Cs aliases the buffers

  // ---- epilogue: stage 32x64 tile (+bias) in LDS, emit attn fragment layouts
  float (*Cs)[68] = (float(*)[68])LDSbuf;  // 32 x 68 f32 = 8704 B (fits 16 KB)
#pragma unroll
  for (int i = 0; i < 4; i++) {
    Cs[mr + quad * 4 + i][nc + lx]      = acc0[i] + bb0;
    Cs[mr + quad * 4 + i][nc + 16 + lx] = acc1[i] + bb1;
  }
  __syncthreads();

  const int bq_ = m0 >> 11;                // batch
  const int s0  = m0 & 2047;               // seq offset within batch
  if (proj == 0) {
    // Q: two 16-row tiles, frag s, lane ll
    const int ti = tid >> 7, s = (tid >> 6) & 1, ll = tid & 63;
    const int lxx = ll & 15, qq = ll >> 4;
    short8 v;
#pragma unroll
    for (int j = 0; j < 8; j++) v[j] = (short)f2bf(Cs[ti * 16 + lxx][s * 32 + qq * 8 + j]);
    char* dst = (char*)Qf + ((size_t)(bq_ * 128 + (s0 >> 4) + ti)) * 2048 + s * 1024 + ll * 16;
    *(short8*)dst = v;
  } else if (proj == 1) {
    // K: half of a 64-row tile -> frags (c0+ci, s)
    const int ci = tid >> 7, s = (tid >> 6) & 1, ll = tid & 63;
    const int lxx = ll & 15, qq = ll >> 4;
    const int c = ((s0 >> 4) & 3) + ci;
    short8 v;
#pragma unroll
    for (int j = 0; j < 8; j++) v[j] = (short)f2bf(Cs[ci * 16 + lxx][s * 32 + qq * 8 + j]);
    char* dst = (char*)Kf + ((size_t)(bq_ * 32 + (s0 >> 6))) * 8192 + (c * 2 + s) * 1024 + ll * 16;
    *(short8*)dst = v;
  } else {
    // V: s-half of a 64-row tile -> frags (sh, c=0..3); lane gathers 8 seq rows
    const int c = tid >> 6, ll = tid & 63;
    const int lxx = ll & 15, qq = ll >> 4;
    const int sh = (s0 >> 5) & 1;
    short8 v;
#pragma unroll
    for (int j = 0; j < 8; j++) v[j] = (short)f2bf(Cs[qq * 8 + j][c * 16 + lxx]);
    char* dst = (char*)Vf + ((size_t)(bq_ * 32 + (s0 >> 6))) * 8192 + (sh * 4 + c) * 1024 + ll * 16;
    *(short8*)dst = v;
  }
}

// ============ flash attention: fragment-major direct loads, 1 barrier =========
// grid (128, 4), 256 threads (4 waves). Block = 16 q-rows; wave w processes
// key-tiles t = w, w+4, ... with independent online-softmax state; merged once.
__global__ __launch_bounds__(256, 2) void attn_kernel(
    const unsigned short* __restrict__ Qf, const unsigned short* __restrict__ Kf,
    const unsigned short* __restrict__ Vf, float* __restrict__ out,
    int R0, int C0, int R1, int C1, int R2, int C2) {
  const int b    = blockIdx.y;
  const int bx   = blockIdx.x;
  const int qi   = (bx & 1) ? (127 - (bx >> 1)) : (bx >> 1);  // heavy/light pairing
  const int q0   = qi * 16;
  const int tid  = threadIdx.x;
  const int w    = tid >> 6;
  const int l    = tid & 63;
  const int quad = l >> 4;
  const int lx   = l & 15;

  __shared__ unsigned short Ps[4][16][72];
  __shared__ float Os[4][16][64];
  __shared__ float mS[4][16], lS[4][16];
  __shared__ float lgS[3];
  __shared__ int   lgF[3];

  const char* Qc = (const char*)Qf + ((size_t)(b * 128 + qi)) * 2048 + l * 16;
  const short8 aq0 = *(const short8*)Qc;
  const short8 aq1 = *(const short8*)(Qc + 1024);

  floatx4 O[4];
  float m_i[4], l_i[4];
#pragma unroll
  for (int c = 0; c < 4; c++) O[c] = (floatx4){0.f, 0.f, 0.f, 0.f};
#pragma unroll
  for (int i = 0; i < 4; i++) { m_i[i] = -INFINITY; l_i[i] = 0.f; }

  const int T = (q0 + 79) >> 6;   // key-tiles needed (64 keys each)

  for (int t = w; t < T; t += 4) {
    const int k0 = t << 6;
    const bool mT = (t == T - 1);

    const char* Kc = (const char*)Kf + ((size_t)(b * 32 + t)) * 8192 + l * 16;
    const char* Vc = (const char*)Vf + ((size_t)(b * 32 + t)) * 8192 + l * 16;
    short8 kf[8], vf[8];
#pragma unroll
    for (int f = 0; f < 8; f++) {
      kf[f] = *(const short8*)(Kc + f * 1024);
      vf[f] = *(const short8*)(Vc + f * 1024);
    }

    floatx4 sc[4];
    __builtin_amdgcn_s_setprio(1);
#pragma unroll
    for (int c = 0; c < 4; c++) {
      sc[c] = (floatx4){0.f, 0.f, 0.f, 0.f};
      sc[c] = MFMA16(aq0, kf[2 * c], sc[c]);
      sc[c] = MFMA16(aq1, kf[2 * c + 1], sc[c]);
    }
    __builtin_amdgcn_s_setprio(0);

    float mt[4], al[4];
#pragma unroll
    for (int i = 0; i < 4; i++) {
      const int rowg = q0 + quad * 4 + i;
      float vmax = -INFINITY;
#pragma unroll
      for (int c = 0; c < 4; c++) {
        float v = sc[c][i] * 0.125f;
        if (mT && (k0 + 16 * c + lx) > rowg) v = -INFINITY;
        sc[c][i] = v;
        vmax = fmaxf(vmax, v);
      }
      mt[i] = vmax;
    }
#pragma unroll
    for (int i = 0; i < 4; i++) {
#pragma unroll
      for (int off = 8; off >= 1; off >>= 1)
        mt[i] = fmaxf(mt[i], __shfl_xor(mt[i], off));
      const float mn = fmaxf(m_i[i], mt[i]);
      al[i] = __expf(m_i[i] - mn);
      m_i[i] = mn;
      float s = 0.f;
#pragma unroll
      for (int c = 0; c < 4; c++) {
        float p = __expf(sc[c][i] - mn);
        Ps[w][quad * 4 + i][16 * c + lx] = f2bf(p);
        s += p;
      }
#pragma unroll
      for (int off = 8; off >= 1; off >>= 1) s += __shfl_xor(s, off);
      l_i[i] = l_i[i] * al[i] + s;
    }
#pragma unroll
    for (int c = 0; c < 4; c++)
#pragma unroll
      for (int i = 0; i < 4; i++) O[c][i] *= al[i];
    asm volatile("" ::: "memory");  // keep ds_reads below the ds_writes above
    const short8 pf0 = *(const short8*)&Ps[w][lx][quad * 8];
    const short8 pf1 = *(const short8*)&Ps[w][lx][32 + quad * 8];
    __builtin_amdgcn_s_setprio(1);
#pragma unroll
    for (int c = 0; c < 4; c++) {
      O[c] = MFMA16(pf0, vf[c],     O[c]);
      O[c] = MFMA16(pf1, vf[4 + c], O[c]);
    }
    __builtin_amdgcn_s_setprio(0);
  }

  // deposit per-wave state
  if (lx == 0) {
#pragma unroll
    for (int i = 0; i < 4; i++) {
      mS[w][quad * 4 + i] = m_i[i];
      lS[w][quad * 4 + i] = l_i[i];
    }
  }
#pragma unroll
  for (int c = 0; c < 4; c++)
#pragma unroll
    for (int i = 0; i < 4; i++) Os[w][quad * 4 + i][16 * c + lx] = O[c][i];

  // wave 0: logits for global pairs above the diagonal (lane l owns dim d=l)
  if (w == 0) {
#pragma unroll
    for (int p = 0; p < 3; p++) {
      const int R = (p == 0) ? R0 : (p == 1) ? R1 : R2;
      const int C = (p == 0) ? C0 : (p == 1) ? C1 : C2;
      const int act = (R >= q0 && R < q0 + 16 && C > R);
      float d = 0.f;
      if (act) {
        const int dd = l;
        const char* qa = (const char*)Qf + ((size_t)(b * 128 + (R >> 4))) * 2048 +
                         (dd >> 5) * 1024 + ((R & 15) + ((dd >> 3) & 3) * 16) * 16 + (dd & 7) * 2;
        const char* ka = (const char*)Kf + ((size_t)(b * 32 + (C >> 6))) * 8192 +
                         (((C >> 4) & 3) * 2 + (dd >> 5)) * 1024 +
                         ((C & 15) + ((dd >> 3) & 3) * 16) * 16 + (dd & 7) * 2;
        d = bf2f(*(const unsigned short*)qa) * bf2f(*(const unsigned short*)ka);
#pragma unroll
        for (int off = 32; off >= 1; off >>= 1) d += __shfl_xor(d, off);
        d *= 0.125f;
      }
      if (l == 0) { lgF[p] = act; lgS[p] = d; }
    }
  }
  __syncthreads();

  // merge the 4 wave states (+ pair fixups), normalize, store
  {
    const int row = tid >> 4;          // 0..15
    const int d0  = (tid & 15) * 4;    // 0..60
    const int Rs[3] = {R0, R1, R2};
    const int Cs3[3] = {C0, C1, C2};

    float mf = -INFINITY;
#pragma unroll
    for (int w4 = 0; w4 < 4; w4++) mf = fmaxf(mf, mS[w4][row]);
#pragma unroll
    for (int p = 0; p < 3; p++)
      if (lgF[p] && (Rs[p] - q0) == row) mf = fmaxf(mf, lgS[p]);

    float lf = 0.f;
    float o0 = 0.f, o1 = 0.f, o2 = 0.f, o3 = 0.f;
#pragma unroll
    for (int w4 = 0; w4 < 4; w4++) {
      const float a = __expf(mS[w4][row] - mf);
      lf += a * lS[w4][row];
      const float* op = &Os[w4][row][d0];
      o0 += a * op[0]; o1 += a * op[1]; o2 += a * op[2]; o3 += a * op[3];
    }
#pragma unroll
    for (int p = 0; p < 3; p++) {
      if (lgF[p] && (Rs[p] - q0) == row) {
        const float pe = __expf(lgS[p] - mf);
        lf += pe;
        const int C = Cs3[p];
        float vv[4];
#pragma unroll
        for (int j = 0; j < 4; j++) {
          const int dim = d0 + j;
          const char* va = (const char*)Vf + ((size_t)(b * 32 + (C >> 6))) * 8192 +
                           (((C >> 5) & 1) * 4 + (dim >> 4)) * 1024 +
                           ((dim & 15) + ((C >> 3) & 3) * 16) * 16 + (C & 7) * 2;
          vv[j] = bf2f(*(const unsigned short*)va);
        }
        o0 += pe * vv[0]; o1 += pe * vv[1]; o2 += pe * vv[2]; o3 += pe * vv[3];
      }
    }
    const float inv = 1.0f / lf;
    float4 r;
    r.x = o0 * inv; r.y = o1 * inv; r.z = o2 * inv; r.w = o3 * inv;
    *(float4*)(out + ((size_t)b * SEQ + q0 + row) * 64 + d0) = r;
  }
}

// ================================= launch =====================================
extern "C" void kernel_launch(void* const* d_in, const int* in_sizes, int n_in,
                              void* d_out, int out_size, void* d_ws,
                              size_t ws_size, hipStream_t stream) {
  const float* xq = (const float*)d_in[0];
  const float* xk = (const float*)d_in[1];
  const float* xv = (const float*)d_in[2];
  const float* Wq = (const float*)d_in[3];
  const float* bq = (const float*)d_in[4];
  const float* Wk = (const float*)d_in[5];
  const float* bk = (const float*)d_in[6];
  const float* Wv = (const float*)d_in[7];
  const float* bv = (const float*)d_in[8];
  float* out = (float*)d_out;

  // workspace (bf16): Qf 1MB, Kf 1MB, Vf 1MB, WTc 384KB (fragment-major layouts)
  unsigned short* Qf  = (unsigned short*)d_ws;
  unsigned short* Kf  = Qf + (size_t)NBATCH * SEQ * 64;
  unsigned short* Vf  = Kf + (size_t)NBATCH * SEQ * 64;
  unsigned short* WTc = Vf + (size_t)NBATCH * SEQ * 64;

  nprng::PCG64 g;
  nprng::pcg_seed_from_seedseq0(g);
  long long rows[3], cols[3];
  nprng::choice3_2048(g, rows);
  nprng::choice3_2048(g, cols);

  wtrans_kernel<<<96, 256, 0, stream>>>(Wq, Wk, Wv, WTc);

  proj_kernel<<<768, 256, 0, stream>>>(xq, xk, xv, WTc, bq, bk, bv, Qf, Kf, Vf);

  dim3 agrid(SEQ / 16, NBATCH);
  attn_kernel<<<agrid, 256, 0, stream>>>(
      Qf, Kf, Vf, out, (int)rows[0], (int)cols[0], (int)rows[1], (int)cols[1],
      (int)rows[2], (int)cols[2]);
}